// Round 11
// baseline (603.357 us; speedup 1.0000x reference)
//
#include <hip/hip_runtime.h>
#include <hip/hip_fp16.h>

// GCN 3-layer forward, MI355X.
// R1 atomics 8.8ms -> R2 CSR gather 1063 -> R3 fp16 869 -> R4 MFMA 718 ->
// R5 fused stats 598 -> R7 recombine 557 -> R10 int2 records 554 ->
// R11: col-only CSR (wgt = dinv[col]*dinv[n] computed in gathers; halves
// scatter's random-write lines), 2-edge vectorized convert, fused prep
// kernels (19 -> 16 dispatches). agg32 at ~122us treated as gather floor.

#define BN_EPS 1e-5f

union HF4 { float4 f; __half2 h[4]; };

typedef __attribute__((ext_vector_type(8))) _Float16 f16x8;
typedef __attribute__((ext_vector_type(4))) float f32x4;

// ---------------- edge-index format probe (int32 vs int64 on device) --------
__global__ void detect_i64(const unsigned int* __restrict__ w, int* flag) {
  __shared__ unsigned int red[256];
  unsigned int v = 0;
  int t = threadIdx.x;
  for (int i = t; i < 1024; i += 256) v |= w[2 * i + 1];
  red[t] = v;
  __syncthreads();
  for (int s = 128; s > 0; s >>= 1) {
    if (t < s) red[t] |= red[t + s];
    __syncthreads();
  }
  if (t == 0) *flag = (red[0] == 0u) ? 1 : 0;
}

// ---------------- edge convert (2 edges/thread) + degree count ---------------
__global__ void convert_deg(const unsigned int* __restrict__ w, const int* __restrict__ flag,
                            int* __restrict__ srcI, int* __restrict__ dstI,
                            int* __restrict__ deg, int E) {
  int i = blockIdx.x * blockDim.x + threadIdx.x;  // pair index
  int e0 = 2 * i;
  if (e0 >= E) return;
  int f = *flag;
  if (e0 + 1 < E) {
    int s0, s1, d0, d1;
    if (f) {
      uint4 sv = ((const uint4*)w)[i];
      uint4 dv = ((const uint4*)(w + 2 * (size_t)E))[i];
      s0 = (int)sv.x; s1 = (int)sv.z;
      d0 = (int)dv.x; d1 = (int)dv.z;
    } else {
      int2 sv = ((const int2*)w)[i];
      int2 dv = ((const int2*)(w + (size_t)E))[i];
      s0 = sv.x; s1 = sv.y;
      d0 = dv.x; d1 = dv.y;
    }
    *(int2*)(srcI + e0) = make_int2(s0, s1);
    *(int2*)(dstI + e0) = make_int2(d0, d1);
    atomicAdd(&deg[d0], 1);
    atomicAdd(&deg[d1], 1);
  } else {
    int s = (int)(f ? w[2 * (size_t)e0] : w[e0]);
    int d = (int)(f ? w[2 * ((size_t)E + e0)] : w[(size_t)E + e0]);
    srcI[e0] = s;
    dstI[e0] = d;
    atomicAdd(&deg[d], 1);
  }
}

// ---------------- prefix scan (tile = 1024), fused dinv + stats zero ---------
__global__ void scan_partial(const int* __restrict__ deg, int* __restrict__ blksum,
                             float* __restrict__ dinv, float* __restrict__ stats, int N) {
  __shared__ int s[256];
  int b = blockIdx.x, t = threadIdx.x;
  if (b == 0) {
    stats[t] = 0.f;
    stats[t + 256] = 0.f;
  }
  int base = b * 1024 + t * 4;
  int v = 0;
#pragma unroll
  for (int k = 0; k < 4; ++k) {
    int i = base + k;
    if (i < N) {
      int dg = deg[i];
      v += dg;
      dinv[i] = rsqrtf((float)dg + 1.0f);
    }
  }
  s[t] = v;
  __syncthreads();
  for (int st = 128; st > 0; st >>= 1) {
    if (t < st) s[t] += s[t + st];
    __syncthreads();
  }
  if (t == 0) blksum[b] = s[0];
}

__global__ void scan_blk(int* __restrict__ blksum, int B) {
  __shared__ int s[256];
  int t = threadIdx.x;
  int v = (t < B) ? blksum[t] : 0;
  s[t] = v;
  __syncthreads();
  for (int off = 1; off < 256; off <<= 1) {
    int u = (t >= off) ? s[t - off] : 0;
    __syncthreads();
    s[t] += u;
    __syncthreads();
  }
  if (t < B) blksum[t] = s[t] - v;
}

// writes rowptr AND a second copy (fill) used as scatter cursors
__global__ void scan_final(const int* __restrict__ deg, const int* __restrict__ blkoff,
                           int* __restrict__ rowptr, int* __restrict__ fill, int N, int E) {
  __shared__ int s[256];
  int b = blockIdx.x, t = threadIdx.x;
  int base = b * 1024 + t * 4;
  int v[4];
  int sum = 0;
#pragma unroll
  for (int k = 0; k < 4; ++k) {
    int i = base + k;
    v[k] = (i < N) ? deg[i] : 0;
    sum += v[k];
  }
  s[t] = sum;
  __syncthreads();
  for (int off = 1; off < 256; off <<= 1) {
    int u = (t >= off) ? s[t - off] : 0;
    __syncthreads();
    s[t] += u;
    __syncthreads();
  }
  int ex = s[t] - sum + blkoff[b];
#pragma unroll
  for (int k = 0; k < 4; ++k) {
    int i = base + k;
    if (i < N) {
      rowptr[i] = ex;
      fill[i] = ex;
      ex += v[k];
    }
  }
  if (b == 0 && t == 0) rowptr[N] = E;
}

// ---------------- CSR scatter: col only (4B random write per edge) -----------
__global__ void csr_scatter(const int* __restrict__ src, const int* __restrict__ dst,
                            int* __restrict__ fill, int* __restrict__ col, int E) {
  int e = blockIdx.x * blockDim.x + threadIdx.x;
  if (e >= E) return;
  int s = src[e], d = dst[e];
  int slot = atomicAdd(&fill[d], 1);
  col[slot] = s;
}

// ---------------- fused prep: weight pack (blocks 0..383) + x->fp16 ----------
__global__ void prep_pack_convert(const float* __restrict__ W0, const float* __restrict__ W1,
                                  _Float16* __restrict__ W0p, _Float16* __restrict__ W1p,
                                  const float4* __restrict__ x, float4* __restrict__ xh,
                                  long n8) {
  long b = blockIdx.x;
  if (b < 384) {
    int idx = (int)b * 256 + threadIdx.x;  // < 384*256
    const float* W = (idx < 128 * 256) ? W0 : W1;
    _Float16* Wp = (idx < 128 * 256) ? W0p : W1p;
    int li = (idx < 128 * 256) ? idx : idx - 128 * 256;
    int k = li >> 8, n = li & 255;
    int kb = k >> 5, kk = k & 31, seg = kk >> 3, j = kk & 7;
    Wp[(((kb * 4 + seg) * 256) + n) * 8 + j] = (_Float16)W[li];
  } else {
    long t = (b - 384) * 256 + threadIdx.x;
    if (t >= n8) return;
    float4 a = x[2 * t], c = x[2 * t + 1];
    HF4 o;
    o.h[0] = __floats2half2_rn(a.x, a.y);
    o.h[1] = __floats2half2_rn(a.z, a.w);
    o.h[2] = __floats2half2_rn(c.x, c.y);
    o.h[3] = __floats2half2_rn(c.z, c.w);
    xh[t] = o.f;
  }
}

// ---------------- gather aggregation (fp16 in/out, fp32 accum) ---------------
// LPN lanes/node, 16B (8 halves) per lane. Unroll 4 (R7-proven: ~40 VGPR,
// ~56-65% occupancy). Edge weight computed on the fly: w = dinv[col]*dinv[n].
// BN: relu(v*scale[c]+shift[c]) applied to every gathered element.
template <int LPN, bool BN>
__global__ void agg_gather_h(const float4* __restrict__ inh, float4* __restrict__ outh,
                             const int* __restrict__ rowptr, const int* __restrict__ col,
                             const float* __restrict__ dinv,
                             const float* __restrict__ scale, const float* __restrict__ shift,
                             int N) {
  long g = (long)blockIdx.x * blockDim.x + threadIdx.x;
  int n = (int)(g / LPN);
  int lane = (int)(g & (LPN - 1));
  if (n >= N) return;
  float sc[8], sh[8];
  if (BN) {
    int c0 = lane * 8;
#pragma unroll
    for (int i = 0; i < 8; ++i) {
      sc[i] = scale[c0 + i];
      sh[i] = shift[c0 + i];
    }
  }
  auto xf = [&](const HF4& u, float* o) {
#pragma unroll
    for (int i = 0; i < 4; ++i) {
      float2 f = __half22float2(u.h[i]);
      o[2 * i] = f.x;
      o[2 * i + 1] = f.y;
    }
    if (BN) {
#pragma unroll
      for (int i = 0; i < 8; ++i) o[i] = fmaxf(o[i] * sc[i] + sh[i], 0.f);
    }
  };
  float dn = dinv[n];
  float ws = dn * dn;
  float acc[8], v[8];
  {
    HF4 u;
    u.f = inh[(long)n * LPN + lane];
    xf(u, v);
#pragma unroll
    for (int i = 0; i < 8; ++i) acc[i] = ws * v[i];
  }
  int beg = rowptr[n], end = rowptr[n + 1];
  int j = beg;
  for (; j + 3 < end; j += 4) {
    int c0 = col[j], c1 = col[j + 1], c2 = col[j + 2], c3 = col[j + 3];
    float w0 = dinv[c0] * dn, w1 = dinv[c1] * dn;
    float w2 = dinv[c2] * dn, w3 = dinv[c3] * dn;
    HF4 a, b, c, d;
    a.f = inh[(long)c0 * LPN + lane];
    b.f = inh[(long)c1 * LPN + lane];
    c.f = inh[(long)c2 * LPN + lane];
    d.f = inh[(long)c3 * LPN + lane];
    float va[8], vb[8], vc[8], vd[8];
    xf(a, va); xf(b, vb); xf(c, vc); xf(d, vd);
#pragma unroll
    for (int i = 0; i < 8; ++i)
      acc[i] += w0 * va[i] + w1 * vb[i] + w2 * vc[i] + w3 * vd[i];
  }
  for (; j < end; ++j) {
    int c0 = col[j];
    float w0 = dinv[c0] * dn;
    HF4 a;
    a.f = inh[(long)c0 * LPN + lane];
    float va[8];
    xf(a, va);
#pragma unroll
    for (int i = 0; i < 8; ++i) acc[i] += w0 * va[i];
  }
  HF4 o;
  o.h[0] = __floats2half2_rn(acc[0], acc[1]);
  o.h[1] = __floats2half2_rn(acc[2], acc[3]);
  o.h[2] = __floats2half2_rn(acc[4], acc[5]);
  o.h[3] = __floats2half2_rn(acc[6], acc[7]);
  outh[(long)n * LPN + lane] = o.f;
}

// ---------------- f16 MFMA GEMM + fused BN stats -----------------------------
// H[M,NC](fp16) = A[M,K](fp16) @ Wpack; per-column sum/sumsq -> gsum/gsq.
// No bias: BN(h+b)==BN(h). Wave = 32 rows x NC cols. Frag layouts per m89.
template <int K, int NC>
__global__ __launch_bounds__(256) void gemm_mfma(const _Float16* __restrict__ A,
                                                 const float4* __restrict__ Wpack,
                                                 _Float16* __restrict__ H,
                                                 float* __restrict__ gsum,
                                                 float* __restrict__ gsq, int M) {
  __shared__ float red0[NC];
  __shared__ float red1[NC];
  int tid = threadIdx.x;
  if (tid < NC) {
    red0[tid] = 0.f;
    red1[tid] = 0.f;
  }
  __syncthreads();
  int wave = tid >> 6;
  int lane = tid & 63;
  int row0 = (blockIdx.x * 4 + wave) * 32;
  bool active = row0 + 31 < M;
  int arow0 = active ? row0 : 0;
  int r = lane & 15;
  int seg = lane >> 4;
  f32x4 acc0[NC / 16], acc1[NC / 16];
#pragma unroll
  for (int t = 0; t < NC / 16; ++t) {
    acc0[t] = (f32x4){0.f, 0.f, 0.f, 0.f};
    acc1[t] = (f32x4){0.f, 0.f, 0.f, 0.f};
  }
  const _Float16* arowA = A + (long)(arow0 + r) * K;
  const _Float16* arowB = A + (long)(arow0 + 16 + r) * K;
#pragma unroll
  for (int k0 = 0; k0 < K; k0 += 32) {
    f16x8 af0 = *(const f16x8*)(arowA + k0 + seg * 8);
    f16x8 af1 = *(const f16x8*)(arowB + k0 + seg * 8);
    const float4* wp = Wpack + ((k0 >> 5) * 4 + seg) * NC;
#pragma unroll
    for (int t = 0; t < NC / 16; ++t) {
      f16x8 bf = *(const f16x8*)(wp + t * 16 + r);
      acc0[t] = __builtin_amdgcn_mfma_f32_16x16x32_f16(af0, bf, acc0[t], 0, 0, 0);
      acc1[t] = __builtin_amdgcn_mfma_f32_16x16x32_f16(af1, bf, acc1[t], 0, 0, 0);
    }
  }
#pragma unroll
  for (int t = 0; t < NC / 16; ++t) {
    int c = t * 16 + r;
    float s = 0.f, q = 0.f;
#pragma unroll
    for (int qq = 0; qq < 4; ++qq) {
      float v0 = acc0[t][qq], v1 = acc1[t][qq];
      s += v0 + v1;
      q += v0 * v0 + v1 * v1;
    }
    s += __shfl_xor(s, 16, 64);
    s += __shfl_xor(s, 32, 64);
    q += __shfl_xor(q, 16, 64);
    q += __shfl_xor(q, 32, 64);
    if (active) {
      if (seg == 0) {
        atomicAdd(&red0[c], s);
        atomicAdd(&red1[c], q);
      }
#pragma unroll
      for (int qq = 0; qq < 4; ++qq) {
        H[(long)(row0 + seg * 4 + qq) * NC + c] = (_Float16)acc0[t][qq];
        H[(long)(row0 + 16 + seg * 4 + qq) * NC + c] = (_Float16)acc1[t][qq];
      }
    }
  }
  __syncthreads();
  if (tid < NC) {
    atomicAdd(&gsum[tid], red0[tid]);
    atomicAdd(&gsq[tid], red1[tid]);
  }
}

// ---------------- BN finalize (re-zeros accumulators for next layer) ---------
__global__ void bn_finalize(float* __restrict__ gsum, float* __restrict__ gsq,
                            const float* __restrict__ gamma, const float* __restrict__ beta,
                            float* __restrict__ scale, float* __restrict__ shift, float invN) {
  int c = threadIdx.x;
  float mean = gsum[c] * invN;
  float var = fmaxf(gsq[c] * invN - mean * mean, 0.f);
  float sc = rsqrtf(var + BN_EPS) * gamma[c];
  scale[c] = sc;
  shift[c] = beta[c] - mean * sc;
  gsum[c] = 0.f;
  gsq[c] = 0.f;
}

// ---------------- BN1 apply + ReLU + layer-2 projection (fused) --------------
__global__ void bn_apply_proj(const float4* __restrict__ h_in, const float* __restrict__ scale,
                              const float* __restrict__ shift, const float* __restrict__ W2,
                              float* __restrict__ P, int N) {
  int tid = threadIdx.x;
  int row = blockIdx.x * 8 + (tid >> 5);
  int lr = tid & 31;
  if (row >= N) return;
  HF4 u;
  u.f = h_in[(long)row * 32 + lr];
  int c0 = lr * 8;
  float s0 = 0.f, s1 = 0.f;
#pragma unroll
  for (int i = 0; i < 4; ++i) {
    float2 f = __half22float2(u.h[i]);
    int ca = c0 + 2 * i, cb = c0 + 2 * i + 1;
    float va = fmaxf(f.x * scale[ca] + shift[ca], 0.f);
    float vb = fmaxf(f.y * scale[cb] + shift[cb], 0.f);
    s0 += va * W2[2 * ca] + vb * W2[2 * cb];
    s1 += va * W2[2 * ca + 1] + vb * W2[2 * cb + 1];
  }
#pragma unroll
  for (int off = 16; off > 0; off >>= 1) {
    s0 += __shfl_down(s0, off, 32);
    s1 += __shfl_down(s1, off, 32);
  }
  if (lr == 0) {
    P[2 * row] = s0;
    P[2 * row + 1] = s1;
  }
}

// ---------------- final 2-dim CSR gather -------------------------------------
__global__ void final_gather(const float* __restrict__ P, float* __restrict__ out,
                             const int* __restrict__ rowptr, const int* __restrict__ col,
                             const float* __restrict__ dinv, const float* __restrict__ b2,
                             int N) {
  int n = blockIdx.x * blockDim.x + threadIdx.x;
  if (n >= N) return;
  float dn = dinv[n];
  float w = dn * dn;
  float a0 = w * P[2 * n + 0];
  float a1 = w * P[2 * n + 1];
  int end = rowptr[n + 1];
  for (int j = rowptr[n]; j < end; ++j) {
    int c = col[j];
    float ww = dinv[c] * dn;
    a0 += ww * P[2 * c + 0];
    a1 += ww * P[2 * c + 1];
  }
  out[2 * n + 0] = a0 + b2[0];
  out[2 * n + 1] = a1 + b2[1];
}

// -----------------------------------------------------------------------------
extern "C" void kernel_launch(void* const* d_in, const int* in_sizes, int n_in,
                              void* d_out, int out_size, void* d_ws, size_t ws_size,
                              hipStream_t stream) {
  const float* x = (const float*)d_in[0];
  const unsigned int* eidx = (const unsigned int*)d_in[1];
  const float* W0 = (const float*)d_in[2];
  const float* W1 = (const float*)d_in[4];
  const float* W2 = (const float*)d_in[6];
  const float* b2 = (const float*)d_in[7];
  const float* gamma0 = (const float*)d_in[8];
  const float* beta0 = (const float*)d_in[9];
  const float* gamma1 = (const float*)d_in[10];
  const float* beta1 = (const float*)d_in[11];

  const int N = in_sizes[0] / 128;  // 100000
  const int E = in_sizes[1] / 2;    // 1600000
  float* out = (float*)d_out;

  char* base = (char*)d_ws;
  size_t off = 0;
  auto alloc = [&](size_t bytes) {
    size_t o = off;
    off = (off + bytes + 255) & ~(size_t)255;
    return o;
  };
  const size_t o_col = alloc((size_t)E * 4);
  const size_t o_rowptr = alloc((size_t)(N + 1) * 4);
  const size_t o_deg = alloc((size_t)N * 4);
  const size_t o_fill = alloc((size_t)N * 4);
  const size_t o_dinv = alloc((size_t)N * 4);
  const size_t o_blk = alloc(1024 * 4);
  const size_t o_flag = alloc(256);
  const size_t o_stats = alloc(4096);
  const size_t o_P = alloc((size_t)N * 2 * 4);
  const size_t o_W0p = alloc(128 * 256 * 2);
  const size_t o_W1p = alloc(256 * 256 * 2);
  const size_t o_H1 = alloc((size_t)N * 256 * 2);  // fp16 ping
  const size_t o_H2 = alloc((size_t)N * 256 * 2);  // fp16 pong (+idx staging)

  int* col = (int*)(base + o_col);
  int* rowptr = (int*)(base + o_rowptr);
  int* deg = (int*)(base + o_deg);
  int* fill = (int*)(base + o_fill);
  float* dinv = (float*)(base + o_dinv);
  int* blk = (int*)(base + o_blk);
  int* flag = (int*)(base + o_flag);
  float* gsum = (float*)(base + o_stats);
  float* gsq = gsum + 256;
  float* scale = gsum + 512;
  float* shift = gsum + 768;
  float* P = (float*)(base + o_P);
  _Float16* W0p = (_Float16*)(base + o_W0p);
  _Float16* W1p = (_Float16*)(base + o_W1p);
  float4* H1 = (float4*)(base + o_H1);
  float4* H2 = (float4*)(base + o_H2);
  int* idx32 = (int*)(base + o_H2);  // staging: dead before H2 first written
  int* srcI = idx32;
  int* dstI = idx32 + E;

  auto cdiv = [](long a, long b) { return (int)((a + b - 1) / b); };
  const float invN = 1.0f / (float)N;
  const int B1 = cdiv(N, 1024);

  // 1. probe dtype; vectorized edge convert + degree count
  hipLaunchKernelGGL(detect_i64, dim3(1), dim3(256), 0, stream, eidx, flag);
  hipMemsetAsync(deg, 0, (size_t)N * 4, stream);
  hipLaunchKernelGGL(convert_deg, dim3(cdiv(cdiv(E, 2), 256)), dim3(256), 0, stream, eidx, flag,
                     srcI, dstI, deg, E);

  // 2. scan (+dinv +stats zero); CSR build (col only); fused pack+convert
  hipLaunchKernelGGL(scan_partial, dim3(B1), dim3(256), 0, stream, deg, blk, dinv, gsum, N);
  hipLaunchKernelGGL(scan_blk, dim3(1), dim3(256), 0, stream, blk, B1);
  hipLaunchKernelGGL(scan_final, dim3(B1), dim3(256), 0, stream, deg, blk, rowptr, fill, N, E);
  hipLaunchKernelGGL(csr_scatter, dim3(cdiv(E, 256)), dim3(256), 0, stream, srcI, dstI, fill,
                     col, E);
  hipLaunchKernelGGL(prep_pack_convert, dim3(384 + cdiv((long)N * 16, 256)), dim3(256), 0,
                     stream, W0, W1, W0p, W1p, (const float4*)x, H1, (long)N * 16);

  // 3. layer 0: agg (128-dim, 16 lanes x 16B, no BN) H1 -> H2; GEMM+stats -> H1
  hipLaunchKernelGGL((agg_gather_h<16, false>), dim3(cdiv((long)N * 16, 256)), dim3(256), 0,
                     stream, H1, H2, rowptr, col, dinv, nullptr, nullptr, N);
  hipLaunchKernelGGL((gemm_mfma<128, 256>), dim3(cdiv(N, 128)), dim3(256), 0, stream,
                     (const _Float16*)H2, (const float4*)W0p, (_Float16*)H1, gsum, gsq, N);

  // 4. BN0 finalize (apply fused into next gather)
  hipLaunchKernelGGL(bn_finalize, dim3(1), dim3(256), 0, stream, gsum, gsq, gamma0, beta0, scale,
                     shift, invN);

  // 5. layer 1: agg (256-dim, 32 lanes x 16B, BN0+ReLU fused) H1 -> H2; GEMM+stats -> H1
  hipLaunchKernelGGL((agg_gather_h<32, true>), dim3(cdiv((long)N * 32, 256)), dim3(256), 0,
                     stream, H1, H2, rowptr, col, dinv, scale, shift, N);
  hipLaunchKernelGGL((gemm_mfma<256, 256>), dim3(cdiv(N, 128)), dim3(256), 0, stream,
                     (const _Float16*)H2, (const float4*)W1p, (_Float16*)H1, gsum, gsq, N);

  // 6. BN1 finalize; fused BN1-apply + ReLU + projection -> P
  hipLaunchKernelGGL(bn_finalize, dim3(1), dim3(256), 0, stream, gsum, gsq, gamma1, beta1, scale,
                     shift, invN);
  hipLaunchKernelGGL(bn_apply_proj, dim3(cdiv(N, 8)), dim3(256), 0, stream, (const float4*)H1,
                     scale, shift, W2, P, N);

  // 7. 2-dim CSR gather into d_out
  hipLaunchKernelGGL(final_gather, dim3(cdiv(N, 256)), dim3(256), 0, stream, P, out, rowptr, col,
                     dinv, b2, N);
}

// Round 12
// 553.596 us; speedup vs baseline: 1.0899x; 1.0899x over previous
//
#include <hip/hip_runtime.h>
#include <hip/hip_fp16.h>

// GCN 3-layer forward, MI355X.
// R1 atomics 8.8ms -> R2 CSR gather 1063 -> R3 fp16 869 -> R4 MFMA 718 ->
// R5 fused stats 598 -> R7 recombine 557 -> R10 int2 records 554 ->
// R11 col-only CSR REGRESSED 603 (random-line touches, not bytes, are the
// scatter cost; on-the-fly weights added dependent random reads to gathers)
// -> R12: R10's int2 {src,wgt} records restored + R11's neutral fusions
// (scan+dinv+stats, pack+convert merged, vectorized convert_deg).

#define BN_EPS 1e-5f

union HF4 { float4 f; __half2 h[4]; };

typedef __attribute__((ext_vector_type(8))) _Float16 f16x8;
typedef __attribute__((ext_vector_type(4))) float f32x4;

// ---------------- edge-index format probe (int32 vs int64 on device) --------
__global__ void detect_i64(const unsigned int* __restrict__ w, int* flag) {
  __shared__ unsigned int red[256];
  unsigned int v = 0;
  int t = threadIdx.x;
  for (int i = t; i < 1024; i += 256) v |= w[2 * i + 1];
  red[t] = v;
  __syncthreads();
  for (int s = 128; s > 0; s >>= 1) {
    if (t < s) red[t] |= red[t + s];
    __syncthreads();
  }
  if (t == 0) *flag = (red[0] == 0u) ? 1 : 0;
}

// ---------------- edge convert (2 edges/thread) + degree count ---------------
__global__ void convert_deg(const unsigned int* __restrict__ w, const int* __restrict__ flag,
                            int* __restrict__ srcI, int* __restrict__ dstI,
                            int* __restrict__ deg, int E) {
  int i = blockIdx.x * blockDim.x + threadIdx.x;  // pair index
  int e0 = 2 * i;
  if (e0 >= E) return;
  int f = *flag;
  if (e0 + 1 < E) {
    int s0, s1, d0, d1;
    if (f) {
      uint4 sv = ((const uint4*)w)[i];
      uint4 dv = ((const uint4*)(w + 2 * (size_t)E))[i];
      s0 = (int)sv.x; s1 = (int)sv.z;
      d0 = (int)dv.x; d1 = (int)dv.z;
    } else {
      int2 sv = ((const int2*)w)[i];
      int2 dv = ((const int2*)(w + (size_t)E))[i];
      s0 = sv.x; s1 = sv.y;
      d0 = dv.x; d1 = dv.y;
    }
    *(int2*)(srcI + e0) = make_int2(s0, s1);
    *(int2*)(dstI + e0) = make_int2(d0, d1);
    atomicAdd(&deg[d0], 1);
    atomicAdd(&deg[d1], 1);
  } else {
    int s = (int)(f ? w[2 * (size_t)e0] : w[e0]);
    int d = (int)(f ? w[2 * ((size_t)E + e0)] : w[(size_t)E + e0]);
    srcI[e0] = s;
    dstI[e0] = d;
    atomicAdd(&deg[d], 1);
  }
}

// ---------------- prefix scan (tile = 1024), fused dinv + stats zero ---------
__global__ void scan_partial(const int* __restrict__ deg, int* __restrict__ blksum,
                             float* __restrict__ dinv, float* __restrict__ stats, int N) {
  __shared__ int s[256];
  int b = blockIdx.x, t = threadIdx.x;
  if (b == 0) {
    stats[t] = 0.f;
    stats[t + 256] = 0.f;
  }
  int base = b * 1024 + t * 4;
  int v = 0;
#pragma unroll
  for (int k = 0; k < 4; ++k) {
    int i = base + k;
    if (i < N) {
      int dg = deg[i];
      v += dg;
      dinv[i] = rsqrtf((float)dg + 1.0f);
    }
  }
  s[t] = v;
  __syncthreads();
  for (int st = 128; st > 0; st >>= 1) {
    if (t < st) s[t] += s[t + st];
    __syncthreads();
  }
  if (t == 0) blksum[b] = s[0];
}

__global__ void scan_blk(int* __restrict__ blksum, int B) {
  __shared__ int s[256];
  int t = threadIdx.x;
  int v = (t < B) ? blksum[t] : 0;
  s[t] = v;
  __syncthreads();
  for (int off = 1; off < 256; off <<= 1) {
    int u = (t >= off) ? s[t - off] : 0;
    __syncthreads();
    s[t] += u;
    __syncthreads();
  }
  if (t < B) blksum[t] = s[t] - v;
}

// writes rowptr AND a second copy (fill) used as scatter cursors
__global__ void scan_final(const int* __restrict__ deg, const int* __restrict__ blkoff,
                           int* __restrict__ rowptr, int* __restrict__ fill, int N, int E) {
  __shared__ int s[256];
  int b = blockIdx.x, t = threadIdx.x;
  int base = b * 1024 + t * 4;
  int v[4];
  int sum = 0;
#pragma unroll
  for (int k = 0; k < 4; ++k) {
    int i = base + k;
    v[k] = (i < N) ? deg[i] : 0;
    sum += v[k];
  }
  s[t] = sum;
  __syncthreads();
  for (int off = 1; off < 256; off <<= 1) {
    int u = (t >= off) ? s[t - off] : 0;
    __syncthreads();
    s[t] += u;
    __syncthreads();
  }
  int ex = s[t] - sum + blkoff[b];
#pragma unroll
  for (int k = 0; k < 4; ++k) {
    int i = base + k;
    if (i < N) {
      rowptr[i] = ex;
      fill[i] = ex;
      ex += v[k];
    }
  }
  if (b == 0 && t == 0) rowptr[N] = E;
}

// ---------------- CSR scatter: ONE combined 8B record per edge (R10) ---------
__global__ void csr_scatter(const int* __restrict__ src, const int* __restrict__ dst,
                            const float* __restrict__ dinv, int* __restrict__ fill,
                            int2* __restrict__ edge, int E) {
  int e = blockIdx.x * blockDim.x + threadIdx.x;
  if (e >= E) return;
  int s = src[e], d = dst[e];
  int slot = atomicAdd(&fill[d], 1);
  edge[slot] = make_int2(s, __float_as_int(dinv[s] * dinv[d]));
}

// ---------------- fused prep: weight pack (blocks 0..383) + x->fp16 ----------
__global__ void prep_pack_convert(const float* __restrict__ W0, const float* __restrict__ W1,
                                  _Float16* __restrict__ W0p, _Float16* __restrict__ W1p,
                                  const float4* __restrict__ x, float4* __restrict__ xh,
                                  long n8) {
  long b = blockIdx.x;
  if (b < 384) {
    int idx = (int)b * 256 + threadIdx.x;  // < 384*256
    const float* W = (idx < 128 * 256) ? W0 : W1;
    _Float16* Wp = (idx < 128 * 256) ? W0p : W1p;
    int li = (idx < 128 * 256) ? idx : idx - 128 * 256;
    int k = li >> 8, n = li & 255;
    int kb = k >> 5, kk = k & 31, seg = kk >> 3, j = kk & 7;
    Wp[(((kb * 4 + seg) * 256) + n) * 8 + j] = (_Float16)W[li];
  } else {
    long t = (b - 384) * 256 + threadIdx.x;
    if (t >= n8) return;
    float4 a = x[2 * t], c = x[2 * t + 1];
    HF4 o;
    o.h[0] = __floats2half2_rn(a.x, a.y);
    o.h[1] = __floats2half2_rn(a.z, a.w);
    o.h[2] = __floats2half2_rn(c.x, c.y);
    o.h[3] = __floats2half2_rn(c.z, c.w);
    xh[t] = o.f;
  }
}

// ---------------- gather aggregation (fp16 in/out, fp32 accum) ---------------
// LPN lanes/node, 16B (8 halves) per lane. Unroll 4 (R7-proven: ~36 VGPR,
// ~65% occupancy). Edge list is combined int2{src, wgt_bits} (R10-proven).
// BN: relu(v*scale[c]+shift[c]) applied to every gathered element.
template <int LPN, bool BN>
__global__ void agg_gather_h(const float4* __restrict__ inh, float4* __restrict__ outh,
                             const int* __restrict__ rowptr, const int2* __restrict__ edge,
                             const float* __restrict__ dinv,
                             const float* __restrict__ scale, const float* __restrict__ shift,
                             int N) {
  long g = (long)blockIdx.x * blockDim.x + threadIdx.x;
  int n = (int)(g / LPN);
  int lane = (int)(g & (LPN - 1));
  if (n >= N) return;
  float sc[8], sh[8];
  if (BN) {
    int c0 = lane * 8;
#pragma unroll
    for (int i = 0; i < 8; ++i) {
      sc[i] = scale[c0 + i];
      sh[i] = shift[c0 + i];
    }
  }
  auto xf = [&](const HF4& u, float* o) {
#pragma unroll
    for (int i = 0; i < 4; ++i) {
      float2 f = __half22float2(u.h[i]);
      o[2 * i] = f.x;
      o[2 * i + 1] = f.y;
    }
    if (BN) {
#pragma unroll
      for (int i = 0; i < 8; ++i) o[i] = fmaxf(o[i] * sc[i] + sh[i], 0.f);
    }
  };
  float dn = dinv[n];
  float ws = dn * dn;
  float acc[8], v[8];
  {
    HF4 u;
    u.f = inh[(long)n * LPN + lane];
    xf(u, v);
#pragma unroll
    for (int i = 0; i < 8; ++i) acc[i] = ws * v[i];
  }
  int beg = rowptr[n], end = rowptr[n + 1];
  int j = beg;
  for (; j + 3 < end; j += 4) {
    int2 e0 = edge[j], e1 = edge[j + 1], e2 = edge[j + 2], e3 = edge[j + 3];
    float w0 = __int_as_float(e0.y), w1 = __int_as_float(e1.y);
    float w2 = __int_as_float(e2.y), w3 = __int_as_float(e3.y);
    HF4 a, b, c, d;
    a.f = inh[(long)e0.x * LPN + lane];
    b.f = inh[(long)e1.x * LPN + lane];
    c.f = inh[(long)e2.x * LPN + lane];
    d.f = inh[(long)e3.x * LPN + lane];
    float va[8], vb[8], vc[8], vd[8];
    xf(a, va); xf(b, vb); xf(c, vc); xf(d, vd);
#pragma unroll
    for (int i = 0; i < 8; ++i)
      acc[i] += w0 * va[i] + w1 * vb[i] + w2 * vc[i] + w3 * vd[i];
  }
  for (; j < end; ++j) {
    int2 e0 = edge[j];
    float w0 = __int_as_float(e0.y);
    HF4 a;
    a.f = inh[(long)e0.x * LPN + lane];
    float va[8];
    xf(a, va);
#pragma unroll
    for (int i = 0; i < 8; ++i) acc[i] += w0 * va[i];
  }
  HF4 o;
  o.h[0] = __floats2half2_rn(acc[0], acc[1]);
  o.h[1] = __floats2half2_rn(acc[2], acc[3]);
  o.h[2] = __floats2half2_rn(acc[4], acc[5]);
  o.h[3] = __floats2half2_rn(acc[6], acc[7]);
  outh[(long)n * LPN + lane] = o.f;
}

// ---------------- f16 MFMA GEMM + fused BN stats -----------------------------
// H[M,NC](fp16) = A[M,K](fp16) @ Wpack; per-column sum/sumsq -> gsum/gsq.
// No bias: BN(h+b)==BN(h). Wave = 32 rows x NC cols. Frag layouts per m89.
template <int K, int NC>
__global__ __launch_bounds__(256) void gemm_mfma(const _Float16* __restrict__ A,
                                                 const float4* __restrict__ Wpack,
                                                 _Float16* __restrict__ H,
                                                 float* __restrict__ gsum,
                                                 float* __restrict__ gsq, int M) {
  __shared__ float red0[NC];
  __shared__ float red1[NC];
  int tid = threadIdx.x;
  if (tid < NC) {
    red0[tid] = 0.f;
    red1[tid] = 0.f;
  }
  __syncthreads();
  int wave = tid >> 6;
  int lane = tid & 63;
  int row0 = (blockIdx.x * 4 + wave) * 32;
  bool active = row0 + 31 < M;
  int arow0 = active ? row0 : 0;
  int r = lane & 15;
  int seg = lane >> 4;
  f32x4 acc0[NC / 16], acc1[NC / 16];
#pragma unroll
  for (int t = 0; t < NC / 16; ++t) {
    acc0[t] = (f32x4){0.f, 0.f, 0.f, 0.f};
    acc1[t] = (f32x4){0.f, 0.f, 0.f, 0.f};
  }
  const _Float16* arowA = A + (long)(arow0 + r) * K;
  const _Float16* arowB = A + (long)(arow0 + 16 + r) * K;
#pragma unroll
  for (int k0 = 0; k0 < K; k0 += 32) {
    f16x8 af0 = *(const f16x8*)(arowA + k0 + seg * 8);
    f16x8 af1 = *(const f16x8*)(arowB + k0 + seg * 8);
    const float4* wp = Wpack + ((k0 >> 5) * 4 + seg) * NC;
#pragma unroll
    for (int t = 0; t < NC / 16; ++t) {
      f16x8 bf = *(const f16x8*)(wp + t * 16 + r);
      acc0[t] = __builtin_amdgcn_mfma_f32_16x16x32_f16(af0, bf, acc0[t], 0, 0, 0);
      acc1[t] = __builtin_amdgcn_mfma_f32_16x16x32_f16(af1, bf, acc1[t], 0, 0, 0);
    }
  }
#pragma unroll
  for (int t = 0; t < NC / 16; ++t) {
    int c = t * 16 + r;
    float s = 0.f, q = 0.f;
#pragma unroll
    for (int qq = 0; qq < 4; ++qq) {
      float v0 = acc0[t][qq], v1 = acc1[t][qq];
      s += v0 + v1;
      q += v0 * v0 + v1 * v1;
    }
    s += __shfl_xor(s, 16, 64);
    s += __shfl_xor(s, 32, 64);
    q += __shfl_xor(q, 16, 64);
    q += __shfl_xor(q, 32, 64);
    if (active) {
      if (seg == 0) {
        atomicAdd(&red0[c], s);
        atomicAdd(&red1[c], q);
      }
#pragma unroll
      for (int qq = 0; qq < 4; ++qq) {
        H[(long)(row0 + seg * 4 + qq) * NC + c] = (_Float16)acc0[t][qq];
        H[(long)(row0 + 16 + seg * 4 + qq) * NC + c] = (_Float16)acc1[t][qq];
      }
    }
  }
  __syncthreads();
  if (tid < NC) {
    atomicAdd(&gsum[tid], red0[tid]);
    atomicAdd(&gsq[tid], red1[tid]);
  }
}

// ---------------- BN finalize (re-zeros accumulators for next layer) ---------
__global__ void bn_finalize(float* __restrict__ gsum, float* __restrict__ gsq,
                            const float* __restrict__ gamma, const float* __restrict__ beta,
                            float* __restrict__ scale, float* __restrict__ shift, float invN) {
  int c = threadIdx.x;
  float mean = gsum[c] * invN;
  float var = fmaxf(gsq[c] * invN - mean * mean, 0.f);
  float sc = rsqrtf(var + BN_EPS) * gamma[c];
  scale[c] = sc;
  shift[c] = beta[c] - mean * sc;
  gsum[c] = 0.f;
  gsq[c] = 0.f;
}

// ---------------- BN1 apply + ReLU + layer-2 projection (fused) --------------
__global__ void bn_apply_proj(const float4* __restrict__ h_in, const float* __restrict__ scale,
                              const float* __restrict__ shift, const float* __restrict__ W2,
                              float* __restrict__ P, int N) {
  int tid = threadIdx.x;
  int row = blockIdx.x * 8 + (tid >> 5);
  int lr = tid & 31;
  if (row >= N) return;
  HF4 u;
  u.f = h_in[(long)row * 32 + lr];
  int c0 = lr * 8;
  float s0 = 0.f, s1 = 0.f;
#pragma unroll
  for (int i = 0; i < 4; ++i) {
    float2 f = __half22float2(u.h[i]);
    int ca = c0 + 2 * i, cb = c0 + 2 * i + 1;
    float va = fmaxf(f.x * scale[ca] + shift[ca], 0.f);
    float vb = fmaxf(f.y * scale[cb] + shift[cb], 0.f);
    s0 += va * W2[2 * ca] + vb * W2[2 * cb];
    s1 += va * W2[2 * ca + 1] + vb * W2[2 * cb + 1];
  }
#pragma unroll
  for (int off = 16; off > 0; off >>= 1) {
    s0 += __shfl_down(s0, off, 32);
    s1 += __shfl_down(s1, off, 32);
  }
  if (lr == 0) {
    P[2 * row] = s0;
    P[2 * row + 1] = s1;
  }
}

// ---------------- final 2-dim CSR gather -------------------------------------
__global__ void final_gather(const float* __restrict__ P, float* __restrict__ out,
                             const int* __restrict__ rowptr, const int2* __restrict__ edge,
                             const float* __restrict__ dinv, const float* __restrict__ b2,
                             int N) {
  int n = blockIdx.x * blockDim.x + threadIdx.x;
  if (n >= N) return;
  float dn = dinv[n];
  float w = dn * dn;
  float a0 = w * P[2 * n + 0];
  float a1 = w * P[2 * n + 1];
  int end = rowptr[n + 1];
  for (int j = rowptr[n]; j < end; ++j) {
    int2 e = edge[j];
    float ww = __int_as_float(e.y);
    a0 += ww * P[2 * e.x + 0];
    a1 += ww * P[2 * e.x + 1];
  }
  out[2 * n + 0] = a0 + b2[0];
  out[2 * n + 1] = a1 + b2[1];
}

// -----------------------------------------------------------------------------
extern "C" void kernel_launch(void* const* d_in, const int* in_sizes, int n_in,
                              void* d_out, int out_size, void* d_ws, size_t ws_size,
                              hipStream_t stream) {
  const float* x = (const float*)d_in[0];
  const unsigned int* eidx = (const unsigned int*)d_in[1];
  const float* W0 = (const float*)d_in[2];
  const float* W1 = (const float*)d_in[4];
  const float* W2 = (const float*)d_in[6];
  const float* b2 = (const float*)d_in[7];
  const float* gamma0 = (const float*)d_in[8];
  const float* beta0 = (const float*)d_in[9];
  const float* gamma1 = (const float*)d_in[10];
  const float* beta1 = (const float*)d_in[11];

  const int N = in_sizes[0] / 128;  // 100000
  const int E = in_sizes[1] / 2;    // 1600000
  float* out = (float*)d_out;

  char* base = (char*)d_ws;
  size_t off = 0;
  auto alloc = [&](size_t bytes) {
    size_t o = off;
    off = (off + bytes + 255) & ~(size_t)255;
    return o;
  };
  const size_t o_edge = alloc((size_t)E * 8);  // combined {src, wgt} records
  const size_t o_rowptr = alloc((size_t)(N + 1) * 4);
  const size_t o_deg = alloc((size_t)N * 4);
  const size_t o_fill = alloc((size_t)N * 4);
  const size_t o_dinv = alloc((size_t)N * 4);
  const size_t o_blk = alloc(1024 * 4);
  const size_t o_flag = alloc(256);
  const size_t o_stats = alloc(4096);
  const size_t o_P = alloc((size_t)N * 2 * 4);
  const size_t o_W0p = alloc(128 * 256 * 2);
  const size_t o_W1p = alloc(256 * 256 * 2);
  const size_t o_H1 = alloc((size_t)N * 256 * 2);  // fp16 ping
  const size_t o_H2 = alloc((size_t)N * 256 * 2);  // fp16 pong (+idx staging)

  int2* edge = (int2*)(base + o_edge);
  int* rowptr = (int*)(base + o_rowptr);
  int* deg = (int*)(base + o_deg);
  int* fill = (int*)(base + o_fill);
  float* dinv = (float*)(base + o_dinv);
  int* blk = (int*)(base + o_blk);
  int* flag = (int*)(base + o_flag);
  float* gsum = (float*)(base + o_stats);
  float* gsq = gsum + 256;
  float* scale = gsum + 512;
  float* shift = gsum + 768;
  float* P = (float*)(base + o_P);
  _Float16* W0p = (_Float16*)(base + o_W0p);
  _Float16* W1p = (_Float16*)(base + o_W1p);
  float4* H1 = (float4*)(base + o_H1);
  float4* H2 = (float4*)(base + o_H2);
  int* idx32 = (int*)(base + o_H2);  // staging: dead before H2 first written
  int* srcI = idx32;
  int* dstI = idx32 + E;

  auto cdiv = [](long a, long b) { return (int)((a + b - 1) / b); };
  const float invN = 1.0f / (float)N;
  const int B1 = cdiv(N, 1024);

  // 1. probe dtype; vectorized staged edge convert + degree count
  hipLaunchKernelGGL(detect_i64, dim3(1), dim3(256), 0, stream, eidx, flag);
  hipMemsetAsync(deg, 0, (size_t)N * 4, stream);
  hipLaunchKernelGGL(convert_deg, dim3(cdiv(cdiv(E, 2), 256)), dim3(256), 0, stream, eidx, flag,
                     srcI, dstI, deg, E);

  // 2. scan (+dinv +stats zero); CSR build (int2 records); fused pack+convert
  hipLaunchKernelGGL(scan_partial, dim3(B1), dim3(256), 0, stream, deg, blk, dinv, gsum, N);
  hipLaunchKernelGGL(scan_blk, dim3(1), dim3(256), 0, stream, blk, B1);
  hipLaunchKernelGGL(scan_final, dim3(B1), dim3(256), 0, stream, deg, blk, rowptr, fill, N, E);
  hipLaunchKernelGGL(csr_scatter, dim3(cdiv(E, 256)), dim3(256), 0, stream, srcI, dstI, dinv,
                     fill, edge, E);
  hipLaunchKernelGGL(prep_pack_convert, dim3(384 + cdiv((long)N * 16, 256)), dim3(256), 0,
                     stream, W0, W1, W0p, W1p, (const float4*)x, H1, (long)N * 16);

  // 3. layer 0: agg (128-dim, 16 lanes x 16B, no BN) H1 -> H2; GEMM+stats -> H1
  hipLaunchKernelGGL((agg_gather_h<16, false>), dim3(cdiv((long)N * 16, 256)), dim3(256), 0,
                     stream, H1, H2, rowptr, edge, dinv, nullptr, nullptr, N);
  hipLaunchKernelGGL((gemm_mfma<128, 256>), dim3(cdiv(N, 128)), dim3(256), 0, stream,
                     (const _Float16*)H2, (const float4*)W0p, (_Float16*)H1, gsum, gsq, N);

  // 4. BN0 finalize (apply fused into next gather)
  hipLaunchKernelGGL(bn_finalize, dim3(1), dim3(256), 0, stream, gsum, gsq, gamma0, beta0, scale,
                     shift, invN);

  // 5. layer 1: agg (256-dim, 32 lanes x 16B, BN0+ReLU fused) H1 -> H2; GEMM+stats -> H1
  hipLaunchKernelGGL((agg_gather_h<32, true>), dim3(cdiv((long)N * 32, 256)), dim3(256), 0,
                     stream, H1, H2, rowptr, edge, dinv, scale, shift, N);
  hipLaunchKernelGGL((gemm_mfma<256, 256>), dim3(cdiv(N, 128)), dim3(256), 0, stream,
                     (const _Float16*)H2, (const float4*)W1p, (_Float16*)H1, gsum, gsq, N);

  // 6. BN1 finalize; fused BN1-apply + ReLU + projection -> P
  hipLaunchKernelGGL(bn_finalize, dim3(1), dim3(256), 0, stream, gsum, gsq, gamma1, beta1, scale,
                     shift, invN);
  hipLaunchKernelGGL(bn_apply_proj, dim3(cdiv(N, 8)), dim3(256), 0, stream, (const float4*)H1,
                     scale, shift, W2, P, N);

  // 7. 2-dim CSR gather into d_out
  hipLaunchKernelGGL(final_gather, dim3(cdiv(N, 256)), dim3(256), 0, stream, P, out, rowptr,
                     edge, dinv, b2, N);
}